// Round 13
// baseline (7740.527 us; speedup 1.0000x reference)
//
#include <hip/hip_runtime.h>
#include <hip/hip_cooperative_groups.h>

namespace cg = cooperative_groups;

typedef _Float16 f16;
typedef __attribute__((ext_vector_type(8))) _Float16 f16x8;
typedef __attribute__((ext_vector_type(4))) float f32x4;
typedef __attribute__((ext_vector_type(2))) unsigned u32x2;
typedef __attribute__((ext_vector_type(4))) unsigned u32x4;

#define NWG      256
#define NTHREADS 768   // 12 waves
#define BB       64
#define TT       512
#define HH       1024
#define HD4      4096
#define VOCABB   128
#define EMBD     128

// LDS layout (bytes)
#define OFF_U0   0        // [16][1024] f16, XOR-swizzled rows : 32768
#define OFF_W1U1 32768    // [16][2048] f16, XOR-swizzled rows : 65536
#define OFF_TW0  98304    // [128][16] f32 : 8192
#define OFF_Z0   106560   // [2][64][16] f32 : 8192
#define OFF_Z1A  114752   // [2][64][16] f32 : 8192
#define OFF_Z1B  122944   // [64][16] f32 : 4096   (ends 127040)
#define OFF_WDC  98304    // phase-C alias: [128][128] f16 swizzled : 32768 (ends 131072)
#define SMEM_BYTES 131072

#define FLAG_ELEMS 256     // wflag[256]

__device__ __forceinline__ float sigf(float x) { return 1.f / (1.f + __expf(-x)); }

// swizzled f16 LDS byte offset: row-major [rows][K], rowstride bytes, XOR bits 4..6
__device__ __forceinline__ int swz(int base, int row, int rowstride, int k) {
    return base + row * rowstride + ((2 * k) ^ ((row & 7) << 4));
}

// Coherence-point (L3-direct) 16B load: bypasses L1/L2 (sc0 sc1).
__device__ __forceinline__ f16x8 ld16sc(const f16* p) {
    f16x8 r;
    asm volatile("global_load_dwordx4 %0, %1, off sc0 sc1"
                 : "=v"(r) : "v"(p) : "memory");
    return r;
}

// Coherence-point 2B store: write-through to L3 (sc0 sc1).
__device__ __forceinline__ void st2sc(f16* p, float v) {
    f16 h = (f16)v;
    unsigned short u;
    __builtin_memcpy(&u, &h, 2);
    asm volatile("global_store_short %0, %1, off sc0 sc1"
                 :: "v"(p), "v"(u) : "memory");
}

__device__ __forceinline__ void post_flag(unsigned* p, unsigned v) {
    asm volatile("global_store_dword %0, %1, off sc0 sc1" :: "v"(p), "v"(v) : "memory");
}

// Wave-parallel spin: all 64 lanes poll 2 flags each (128 flags), one L3 trip/poll.
__device__ __forceinline__ void wait128(const unsigned* flags, unsigned epoch, int lane) {
    const unsigned* p = flags + 2 * lane;
    for (;;) {
        u32x2 v;
        asm volatile("global_load_dwordx2 %0, %1, off sc0 sc1\n\ts_waitcnt vmcnt(0)"
                     : "=v"(v) : "v"(p) : "memory");
        if (__all((int)(v.x >= epoch && v.y >= epoch))) break;
        __builtin_amdgcn_s_sleep(1);
    }
}

// 256 flags: 4 per lane.
__device__ __forceinline__ void wait256(const unsigned* flags, unsigned epoch, int lane) {
    const unsigned* p = flags + 4 * lane;
    for (;;) {
        u32x4 v;
        asm volatile("global_load_dwordx4 %0, %1, off sc0 sc1\n\ts_waitcnt vmcnt(0)"
                     : "=v"(v) : "v"(p) : "memory");
        if (__all((int)(v.x >= epoch && v.y >= epoch && v.z >= epoch && v.w >= epoch))) break;
        __builtin_amdgcn_s_sleep(1);
    }
}

// Skew audit (wflag alone replaces the grid barrier):
//  - wflag[g] = s+1 is posted after block g's step-s gate stores are committed
//    (per-wave vmcnt(0) before syncthreads(B), flag posted after (B)).
//  - Reader waves at step s spin wflag >= s before loading h-state; the union
//    of a block's waves (0-3: flags 0-127, 4-7: 128-255, 8-11: all) covers all
//    256 producers and is joined at syncthreads(A).
//  - Gate stores at step s overwrite parity (s+1)&1, whose last readers ran at
//    step s-1; those reads completed before any wflag = s was posted, and the
//    gate runs after syncthreads(A) where all 256 wflag >= s were observed.
//    Hence no live reader of the overwrite target exists (no lflag needed).
//  - All h-path stores/loads are sc0sc1 (coherence point): flag-visible =>
//    data-visible; zero cache-maintenance ops in the loop.

__global__ __launch_bounds__(NTHREADS, 3)
void lstm_fused(const int* __restrict__ tokens, const float* __restrict__ emb,
                const float* __restrict__ W0, const float* __restrict__ U0,
                const float* __restrict__ b0, const float* __restrict__ W1,
                const float* __restrict__ U1, const float* __restrict__ b1,
                const float* __restrict__ Wd, const float* __restrict__ bd,
                f16* __restrict__ wsh, float* __restrict__ out)
{
    extern __shared__ char smem[];
    cg::grid_group grid = cg::this_grid();
    const int g    = blockIdx.x;    // 0..255, owns gate-cols {gate*1024 + 4g + d}
    const int tid  = threadIdx.x;
    const int lane = tid & 63;
    const int wave = tid >> 6;

    // workspace (f16 units)
    f16* h1seq = wsh;                              // [B][T][H]
    f16* h0st  = wsh + (size_t)BB * TT * HH;       // [2][B][H]
    f16* h1st  = h0st + 2 * BB * HH;               // [2][B][H]
    unsigned* wflag = (unsigned*)(h1st + 2 * BB * HH); // [256] data-ready epochs

    // ---------------- Phase A: init ----------------
    {   // zero h-state double buffers (4*B*H f16 = 131072 u32; 512 u32 per WG)
        unsigned int* zp = (unsigned int*)h0st;
        for (int i = tid; i < 512; i += NTHREADS) zp[g * 512 + i] = 0u;
        if (g == 0)
            for (int i = tid; i < FLAG_ELEMS; i += NTHREADS) wflag[i] = 0u;
    }
    {   // stage U0 / [W1;U1] column slices into LDS as f16, transposed+swizzled
        const int c = tid & 15;                       // local col: gate*4 + delta
        const int orig = ((c >> 2) * HH) + 4 * g + (c & 3);
        for (int k = tid >> 4; k < HH; k += 48) {
            *(f16*)(smem + swz(OFF_U0, c, 2048, k))        = (f16)U0[(size_t)k * HD4 + orig];
            *(f16*)(smem + swz(OFF_W1U1, c, 4096, k))      = (f16)W1[(size_t)k * HD4 + orig];
            *(f16*)(smem + swz(OFF_W1U1, c, 4096, k + HH)) = (f16)U1[(size_t)k * HD4 + orig];
        }
    }
    // TW0 = emb @ W0 + b0, our 16-column slice (f32, exact)
    for (int idx = tid; idx < VOCABB * 16; idx += NTHREADS) {
        int v = idx >> 4, c = idx & 15;
        int orig = ((c >> 2) * HH) + 4 * g + (c & 3);
        float acc = b0[orig];
        for (int e = 0; e < EMBD; ++e)
            acc += emb[v * EMBD + e] * W0[(size_t)e * HD4 + orig];
        ((float*)(smem + OFF_TW0))[idx] = acc;
    }
    __syncthreads();
    grid.sync();      // one-time full release/acquire: publishes zeros + flag state

    // ---------------- Phase B: 513 pipelined supersteps ----------------
    float c0 = 0.f, c1 = 0.f;                 // cell states in gate-thread regs
    const int gb = tid >> 2, gd = tid & 3;    // gate thread: batch, delta
    float* z0buf  = (float*)(smem + OFF_Z0);
    float* z1abuf = (float*)(smem + OFF_Z1A);
    float* z1bbuf = (float*)(smem + OFF_Z1B);
    float* TW0s   = (float*)(smem + OFF_TW0);

    float b1r0 = 0.f, b1r1 = 0.f, b1r2 = 0.f, b1r3 = 0.f;
    if (tid < 256) {
        b1r0 = b1[0 * HH + 4 * g + gd];
        b1r1 = b1[1 * HH + 4 * g + gd];
        b1r2 = b1[2 * HH + 4 * g + gd];
        b1r3 = b1[3 * HH + 4 * g + gd];
    }

    for (int s = 0; s <= TT; ++s) {
        const f16* h0r = h0st + (size_t)(s & 1) * BB * HH;
        const f16* h1r = h1st + (size_t)(s & 1) * BB * HH;
        const int n  = lane & 15;
        const int kq = 8 * (lane >> 4);

        if (wave < 8) {
            const int mt = wave & 3, kh = wave >> 2;
            // wait only for the producers of our k-slice (cols kh*512..+512)
            wait128(wflag + kh * 128, (unsigned)s, lane);
            const int arow = mt * 16 + (lane & 15);
            const f16* aptr = &h0r[(size_t)arow * HH + kh * 512 + kq];
            f16x8 av[16];
            #pragma unroll
            for (int ki = 0; ki < 16; ++ki)
                av[ki] = ld16sc(aptr + ki * 32);    // 16 L3-direct loads in flight
            asm volatile("s_waitcnt vmcnt(0)" ::: "memory");
            __builtin_amdgcn_sched_barrier(0);
            f32x4 a0 = {0.f, 0.f, 0.f, 0.f}, a1 = {0.f, 0.f, 0.f, 0.f};
            #pragma unroll
            for (int ki = 0; ki < 16; ++ki) {
                int k = kh * 512 + ki * 32 + kq;
                f16x8 bv0 = *(const f16x8*)(smem + swz(OFF_U0, n, 2048, k));
                a0 = __builtin_amdgcn_mfma_f32_16x16x32_f16(av[ki], bv0, a0, 0, 0, 0);
                f16x8 bv1 = *(const f16x8*)(smem + swz(OFF_W1U1, n, 4096, k));
                a1 = __builtin_amdgcn_mfma_f32_16x16x32_f16(av[ki], bv1, a1, 0, 0, 0);
            }
            int r0 = mt * 16 + (lane >> 4) * 4;
            #pragma unroll
            for (int r = 0; r < 4; ++r) {
                z0buf [(kh * 64 + r0 + r) * 16 + n] = a0[r];
                z1abuf[(kh * 64 + r0 + r) * 16 + n] = a1[r];
            }
        } else {
            // h1 path: h1_{t-1} @ U1 — needs all 256 producers
            wait256(wflag, (unsigned)s, lane);
            const int mt = wave & 3;
            const int arow = mt * 16 + (lane & 15);
            const f16* aptr = &h1r[(size_t)arow * HH + kq];
            f32x4 a1 = {0.f, 0.f, 0.f, 0.f};
            #pragma unroll
            for (int half = 0; half < 2; ++half) {
                f16x8 av[16];
                #pragma unroll
                for (int ki = 0; ki < 16; ++ki)
                    av[ki] = ld16sc(aptr + half * 512 + ki * 32);
                asm volatile("s_waitcnt vmcnt(0)" ::: "memory");
                __builtin_amdgcn_sched_barrier(0);
                #pragma unroll
                for (int ki = 0; ki < 16; ++ki) {
                    int k = half * 512 + ki * 32 + kq;
                    f16x8 bv = *(const f16x8*)(smem + swz(OFF_W1U1, n, 4096, k + HH));
                    a1 = __builtin_amdgcn_mfma_f32_16x16x32_f16(av[ki], bv, a1, 0, 0, 0);
                }
            }
            int r0 = mt * 16 + (lane >> 4) * 4;
            #pragma unroll
            for (int r = 0; r < 4; ++r) z1bbuf[(r0 + r) * 16 + n] = a1[r];
        }
        __syncthreads();                                    // (A) z ready; all 256
                                                            //     wflag >= s observed

        if (wave < 4) {
            const int j = 4 * g + gd;
            if (s < TT) {   // layer 0, step t = s
                int tok = tokens[gb * TT + s];
                float zi = z0buf[gb * 16 +  0 + gd] + z0buf[(64 + gb) * 16 +  0 + gd] + TW0s[tok * 16 +  0 + gd];
                float zf = z0buf[gb * 16 +  4 + gd] + z0buf[(64 + gb) * 16 +  4 + gd] + TW0s[tok * 16 +  4 + gd];
                float zg = z0buf[gb * 16 +  8 + gd] + z0buf[(64 + gb) * 16 +  8 + gd] + TW0s[tok * 16 +  8 + gd];
                float zo = z0buf[gb * 16 + 12 + gd] + z0buf[(64 + gb) * 16 + 12 + gd] + TW0s[tok * 16 + 12 + gd];
                c0 = sigf(zf) * c0 + sigf(zi) * tanhf(zg);
                float h0v = sigf(zo) * tanhf(c0);
                st2sc(&h0st[(size_t)((s + 1) & 1) * BB * HH + (size_t)gb * HH + j], h0v);
            }
            if (s >= 1) {   // layer 1, step t = s-1
                float zi = z1abuf[gb * 16 +  0 + gd] + z1abuf[(64 + gb) * 16 +  0 + gd] + z1bbuf[gb * 16 +  0 + gd] + b1r0;
                float zf = z1abuf[gb * 16 +  4 + gd] + z1abuf[(64 + gb) * 16 +  4 + gd] + z1bbuf[gb * 16 +  4 + gd] + b1r1;
                float zg = z1abuf[gb * 16 +  8 + gd] + z1abuf[(64 + gb) * 16 +  8 + gd] + z1bbuf[gb * 16 +  8 + gd] + b1r2;
                float zo = z1abuf[gb * 16 + 12 + gd] + z1abuf[(64 + gb) * 16 + 12 + gd] + z1bbuf[gb * 16 + 12 + gd] + b1r3;
                c1 = sigf(zf) * c1 + sigf(zi) * tanhf(zg);
                float h1v = sigf(zo) * tanhf(c1);
                st2sc(&h1st[(size_t)((s + 1) & 1) * BB * HH + (size_t)gb * HH + j], h1v);
                st2sc(&h1seq[((size_t)gb * TT + (s - 1)) * HH + j], h1v);
            }
            asm volatile("s_waitcnt vmcnt(0)" ::: "memory");  // h stores committed
        }
        __syncthreads();                                      // (B) block-wide drain
        if (tid == 0) post_flag(&wflag[g], (unsigned)(s + 1));
    }

    // all blocks' final h1seq stores visible before the output GEMM
    wait256(wflag, (unsigned)(TT + 1), lane);

    // ---------------- Phase C: logits = h1seq @ Wd + bd ----------------
    // h1seq was written sc0sc1 (no L2 allocation anywhere) -> plain cached reads
    // below fetch fresh data from L3; no fence needed.
    {
        const int r0 = g * 128;               // 128 (b,t)-rows per CU
        f32x4 accC[6];
        #pragma unroll
        for (int i = 0; i < 6; ++i) accC[i] = (f32x4){0.f, 0.f, 0.f, 0.f};

        for (int kc = 0; kc < 8; ++kc) {
            __syncthreads();
            // stage Wd K-chunk [128k][128n] -> LDS [n][k] f16 swizzled
            for (int idx = tid; idx < 128 * 128; idx += NTHREADS) {
                int kk = idx >> 7, nn = idx & 127;
                *(f16*)(smem + swz(OFF_WDC, nn, 256, kk)) = (f16)Wd[(size_t)(kc * 128 + kk) * 128 + nn];
            }
            __syncthreads();
            int ti = 0;
            for (int tile = wave; tile < 64; tile += 12, ++ti) {
                int mt = tile >> 3, nt = tile & 7;
                int arow = r0 + mt * 16 + (lane & 15);
                int kq = 8 * (lane >> 4);
                int nn = nt * 16 + (lane & 15);
                f32x4 acc = accC[ti];
                #pragma unroll
                for (int k4 = 0; k4 < 4; ++k4) {
                    int k = kc * 128 + k4 * 32 + kq;
                    f16x8 av = *(const f16x8*)&h1seq[(size_t)arow * HH + k];
                    f16x8 bv = *(const f16x8*)(smem + swz(OFF_WDC, nn, 256, k4 * 32 + kq));
                    acc = __builtin_amdgcn_mfma_f32_16x16x32_f16(av, bv, acc, 0, 0, 0);
                }
                accC[ti] = acc;
            }
        }
        int ti = 0;
        for (int tile = wave; tile < 64; tile += 12, ++ti) {
            int mt = tile >> 3, nt = tile & 7;
            int row0 = r0 + mt * 16 + (lane >> 4) * 4;
            int col  = nt * 16 + (lane & 15);
            float bdv = bd[col];
            #pragma unroll
            for (int r = 0; r < 4; ++r)
                out[(size_t)(row0 + r) * 128 + col] = accC[ti][r] + bdv;
        }
    }
}

extern "C" void kernel_launch(void* const* d_in, const int* in_sizes, int n_in,
                              void* d_out, int out_size, void* d_ws, size_t ws_size,
                              hipStream_t stream) {
    const int*   tokens = (const int*)d_in[0];
    const float* emb    = (const float*)d_in[1];
    const float* W0     = (const float*)d_in[2];
    const float* U0     = (const float*)d_in[3];
    const float* b0     = (const float*)d_in[4];
    const float* W1     = (const float*)d_in[5];
    const float* U1     = (const float*)d_in[6];
    const float* b1     = (const float*)d_in[7];
    const float* Wd     = (const float*)d_in[8];
    const float* bd     = (const float*)d_in[9];
    float* out = (float*)d_out;
    f16*   ws  = (f16*)d_ws;

    (void)hipFuncSetAttribute((const void*)lstm_fused,
                              hipFuncAttributeMaxDynamicSharedMemorySize, SMEM_BYTES);

    void* args[] = { &tokens, &emb, &W0, &U0, &b0, &W1, &U1, &b1, &Wd, &bd, &ws, &out };
    (void)hipLaunchCooperativeKernel((const void*)lstm_fused, dim3(NWG), dim3(NTHREADS),
                                     args, SMEM_BYTES, stream);
}